// Round 1
// baseline (5736.843 us; speedup 1.0000x reference)
//
#include <hip/hip_runtime.h>
#include <float.h>

#define NB 64
#define NP 1024
#define KNN 10

__device__ __forceinline__ float lrelu(float v){ return v >= 0.0f ? v : 0.01f*v; }

// ---------------- kernel 1: build xx = concat(x, pos) ----------------
__global__ void build_xx(const float* __restrict__ x, const float* __restrict__ pos,
                         float* __restrict__ xx){
  int n = blockIdx.x*256 + threadIdx.x;
  float4 v;
  v.x = x[n];
  v.y = pos[3*n+0];
  v.z = pos[3*n+1];
  v.w = pos[3*n+2];
  ((float4*)xx)[n] = v;
}

// ---------------- kernel 2: knn on 4-dim features ----------------
__global__ __launch_bounds__(256,4) void knn1_kernel(const float* __restrict__ xx,
                                                     int* __restrict__ idx1){
  __shared__ float sf[NP*4];
  __shared__ float ssq[NP];
  int b = blockIdx.x >> 2;
  int q = blockIdx.x & 3;
  const float4* base = (const float4*)(xx + (size_t)b*NP*4);
  for (int t = threadIdx.x; t < NP; t += 256){
    float4 v = base[t];
    ((float4*)sf)[t] = v;
    ssq[t] = ((v.x*v.x + v.y*v.y) + v.z*v.z) + v.w*v.w;
  }
  __syncthreads();
  int il = q*256 + threadIdx.x;
  float4 fi = ((float4*)sf)[il];
  float sqi = ssq[il];
  float bd[KNN]; int bi[KNN];
  #pragma unroll
  for (int s=0;s<KNN;++s){ bd[s]=FLT_MAX; bi[s]=0; }
  for (int j=0;j<NP;++j){
    float4 fj = ((float4*)sf)[j];
    float dot = fi.x*fj.x + fi.y*fj.y + fi.z*fj.z + fi.w*fj.w;
    float d2 = (sqi + ssq[j]) - 2.0f*dot;
    if (d2 < bd[KNN-1]){
      float dk=d2; int ik=j;
      #pragma unroll
      for (int s=0;s<KNN;++s){
        bool sw = dk < bd[s];
        float td=bd[s]; int ti=bi[s];
        bd[s]=sw?dk:td; bi[s]=sw?ik:ti;
        dk=sw?td:dk;    ik=sw?ti:ik;
      }
    }
  }
  int n = b*NP + il;
  #pragma unroll
  for (int s=0;s<KNN;++s) idx1[n*KNN+s]=bi[s];
}

// ---------------- kernel 3: edgeconv1 (8->64->64->64, sum over K) ----------------
__global__ __launch_bounds__(256,1) void edgeconv1_kernel(
    const float* __restrict__ xx, const int* __restrict__ idx1,
    const float* __restrict__ w1a, const float* __restrict__ b1a,
    const float* __restrict__ w1b, const float* __restrict__ b1b,
    const float* __restrict__ w1c, const float* __restrict__ b1c,
    float* __restrict__ x1, float* __restrict__ sq2){
  __shared__ float sf[NP*4];
  int b = blockIdx.x >> 2;
  int q = blockIdx.x & 3;
  const float4* base = (const float4*)(xx + (size_t)b*NP*4);
  for (int t = threadIdx.x; t < NP; t += 256) ((float4*)sf)[t] = base[t];
  __syncthreads();
  int il = q*256 + threadIdx.x;
  int n = b*NP + il;
  float4 fi = ((float4*)sf)[il];
  float acc[64];
  #pragma unroll
  for (int o=0;o<64;++o) acc[o]=0.0f;
  for (int k=0;k<KNN;++k){
    int j = idx1[n*KNN+k];
    float4 fj = ((float4*)sf)[j];
    float e[8];
    e[0]=fi.x; e[1]=fi.y; e[2]=fi.z; e[3]=fi.w;
    e[4]=fj.x-fi.x; e[5]=fj.y-fi.y; e[6]=fj.z-fi.z; e[7]=fj.w-fi.w;
    float h1[64];
    #pragma unroll
    for (int o=0;o<64;++o){
      float t = b1a[o];
      #pragma unroll
      for (int c=0;c<8;++c) t = fmaf(e[c], w1a[c*64+o], t);
      h1[o] = lrelu(t);
    }
    float h2[64];
    #pragma unroll
    for (int o=0;o<64;++o){
      float t = b1b[o];
      #pragma unroll
      for (int c=0;c<64;++c) t = fmaf(h1[c], w1b[c*64+o], t);
      h2[o] = lrelu(t);
    }
    #pragma unroll
    for (int o=0;o<64;++o){
      float t = b1c[o];
      #pragma unroll
      for (int c=0;c<64;++c) t = fmaf(h2[c], w1c[c*64+o], t);
      acc[o] += lrelu(t);
    }
  }
  float s = 0.0f;
  #pragma unroll
  for (int o=0;o<64;++o){
    x1[(size_t)n*64+o] = acc[o];
    s = fmaf(acc[o], acc[o], s);
  }
  sq2[n] = s;
}

// ---------------- kernel 4: knn on 64-dim features ----------------
__global__ __launch_bounds__(256,2) void knn2_kernel(const float* __restrict__ x1,
                                                     const float* __restrict__ sq2,
                                                     int* __restrict__ idx2){
  __shared__ float sj[256*64];
  __shared__ float ssq[256];
  int b = blockIdx.x >> 2;
  int q = blockIdx.x & 3;
  int il = q*256 + threadIdx.x;
  int n = b*NP + il;
  float xi[64];
  #pragma unroll
  for (int c=0;c<64;c+=4){
    float4 v = *(const float4*)&x1[(size_t)n*64+c];
    xi[c]=v.x; xi[c+1]=v.y; xi[c+2]=v.z; xi[c+3]=v.w;
  }
  float sqi = sq2[n];
  float bd[KNN]; int bi[KNN];
  #pragma unroll
  for (int s=0;s<KNN;++s){ bd[s]=FLT_MAX; bi[s]=0; }
  for (int tile=0; tile<4; ++tile){
    __syncthreads();
    const float4* src = (const float4*)(x1 + ((size_t)b*NP + tile*256)*64);
    for (int t=threadIdx.x; t<256*16; t+=256) ((float4*)sj)[t] = src[t];
    ssq[threadIdx.x] = sq2[b*NP + tile*256 + threadIdx.x];
    __syncthreads();
    for (int j=0;j<256;++j){
      float dot = 0.0f;
      #pragma unroll
      for (int c=0;c<64;c+=4){
        float4 v = *(const float4*)&sj[j*64+c];
        dot = fmaf(xi[c+0], v.x, dot);
        dot = fmaf(xi[c+1], v.y, dot);
        dot = fmaf(xi[c+2], v.z, dot);
        dot = fmaf(xi[c+3], v.w, dot);
      }
      float d2 = (sqi + ssq[j]) - 2.0f*dot;
      if (d2 < bd[KNN-1]){
        float dk=d2; int ik=tile*256+j;
        #pragma unroll
        for (int s=0;s<KNN;++s){
          bool sw = dk < bd[s];
          float td=bd[s]; int ti=bi[s];
          bd[s]=sw?dk:td; bi[s]=sw?ik:ti;
          dk=sw?td:dk;    ik=sw?ti:ik;
        }
      }
    }
  }
  #pragma unroll
  for (int s=0;s<KNN;++s) idx2[n*KNN+s]=bi[s];
}

// ---------------- kernel 5: edgeconv2 (128->128, sum over K), split by output half ----------------
__global__ __launch_bounds__(256,1) void edgeconv2_kernel(
    const float* __restrict__ x1, const int* __restrict__ idx2,
    const float* __restrict__ w2, const float* __restrict__ b2,
    float* __restrict__ x2){
  int bid = blockIdx.x;
  int half = bid >> 8;           // grid 512: 0..255 -> half 0, 256..511 -> half 1
  int pb  = bid & 255;
  int n = pb*256 + threadIdx.x;  // global point id
  int b = n >> 10;
  int ob = half*64;
  float xi[64];
  #pragma unroll
  for (int c=0;c<64;c+=4){
    float4 v = *(const float4*)&x1[(size_t)n*64+c];
    xi[c]=v.x; xi[c+1]=v.y; xi[c+2]=v.z; xi[c+3]=v.w;
  }
  float acc[64];
  #pragma unroll
  for (int o=0;o<64;++o) acc[o]=0.0f;
  for (int k=0;k<KNN;++k){
    int j = idx2[n*KNN+k];
    const float* xjp = x1 + ((size_t)(b*NP + j))*64;
    float xd[64];   // xj - xi
    #pragma unroll
    for (int c=0;c<64;c+=4){
      float4 v = *(const float4*)&xjp[c];
      xd[c]=v.x-xi[c]; xd[c+1]=v.y-xi[c+1]; xd[c+2]=v.z-xi[c+2]; xd[c+3]=v.w-xi[c+3];
    }
    #pragma unroll
    for (int o=0;o<64;++o){
      float t = b2[ob+o];
      #pragma unroll
      for (int c=0;c<64;++c) t = fmaf(xi[c], w2[c*128 + ob + o], t);
      #pragma unroll
      for (int c=0;c<64;++c) t = fmaf(xd[c], w2[(64+c)*128 + ob + o], t);
      acc[o] += lrelu(t);
    }
  }
  #pragma unroll
  for (int o=0;o<64;++o) x2[(size_t)n*128 + ob + o] = acc[o];
}

// ---------------- kernel 6: mean over points -> (64, 192) ----------------
__global__ __launch_bounds__(192) void mean_kernel(const float* __restrict__ x1,
                                                   const float* __restrict__ x2,
                                                   float* __restrict__ fmean){
  int b = blockIdx.x;
  int c = threadIdx.x;   // 0..191
  float acc = 0.0f;
  if (c < 64){
    const float* p = x1 + (size_t)b*NP*64 + c;
    for (int i=0;i<NP;++i) acc += p[(size_t)i*64];
  } else {
    int cc = c - 64;
    const float* p = x2 + (size_t)b*NP*128 + cc;
    for (int i=0;i<NP;++i) acc += p[(size_t)i*128];
  }
  fmean[b*192 + c] = acc * (1.0f/1024.0f);
}

// ---------------- kernel 7: head (192->1024 ->512->256->3) ----------------
__global__ __launch_bounds__(256) void head_kernel(
    const float* __restrict__ fmean,
    const float* __restrict__ wl,  const float* __restrict__ bl,
    const float* __restrict__ wm1, const float* __restrict__ bm1,
    const float* __restrict__ wm2, const float* __restrict__ bm2,
    const float* __restrict__ wm3, const float* __restrict__ bm3,
    float* __restrict__ out){
  __shared__ float v0[192];
  __shared__ float o1[1024];
  __shared__ float h1[512];
  __shared__ float h2[256];
  int b = blockIdx.x, t = threadIdx.x;
  if (t < 192) v0[t] = fmean[b*192 + t];
  __syncthreads();
  #pragma unroll
  for (int r=0;r<4;++r){
    int o = r*256 + t;
    float s = bl[o];
    #pragma unroll 8
    for (int c=0;c<192;++c) s = fmaf(v0[c], wl[c*1024 + o], s);
    o1[o] = s;   // no activation on this layer
  }
  __syncthreads();
  #pragma unroll
  for (int r=0;r<2;++r){
    int o = r*256 + t;
    float s = bm1[o];
    #pragma unroll 8
    for (int c=0;c<1024;++c) s = fmaf(o1[c], wm1[c*512 + o], s);
    h1[o] = lrelu(s);
  }
  __syncthreads();
  {
    int o = t;
    float s = bm2[o];
    #pragma unroll 8
    for (int c=0;c<512;++c) s = fmaf(h1[c], wm2[c*256 + o], s);
    h2[o] = lrelu(s);
  }
  __syncthreads();
  if (t < 3){
    float s = bm3[t];
    #pragma unroll 8
    for (int c=0;c<256;++c) s = fmaf(h2[c], wm3[c*3 + t], s);
    out[b*3 + t] = s;
  }
}

extern "C" void kernel_launch(void* const* d_in, const int* in_sizes, int n_in,
                              void* d_out, int out_size, void* d_ws, size_t ws_size,
                              hipStream_t stream) {
  const float* x   = (const float*)d_in[0];
  const float* pos = (const float*)d_in[1];
  // d_in[2] = batch (unused; layout is implicit)
  const float* w1a = (const float*)d_in[3];
  const float* b1a = (const float*)d_in[4];
  const float* w1b = (const float*)d_in[5];
  const float* b1b = (const float*)d_in[6];
  const float* w1c = (const float*)d_in[7];
  const float* b1c = (const float*)d_in[8];
  const float* w2  = (const float*)d_in[9];
  const float* b2  = (const float*)d_in[10];
  const float* wl  = (const float*)d_in[11];
  const float* bl  = (const float*)d_in[12];
  const float* wm1 = (const float*)d_in[13];
  const float* bm1 = (const float*)d_in[14];
  const float* wm2 = (const float*)d_in[15];
  const float* bm2 = (const float*)d_in[16];
  const float* wm3 = (const float*)d_in[17];
  const float* bm3 = (const float*)d_in[18];
  float* out = (float*)d_out;

  char* ws = (char*)d_ws;
  const size_t N = (size_t)NB*NP;        // 65536
  float* xx    = (float*)(ws);                               // N*4      =  1 MB
  float* x1    = (float*)(ws + 1048576);                     // N*64     = 16 MB
  float* x2    = (float*)(ws + 1048576 + 16777216);          // N*128    = 32 MB
  float* sq2   = (float*)(ws + 1048576 + 16777216 + 33554432);           // N floats
  int*   idx1  = (int*)  (ws + 1048576 + 16777216 + 33554432 + 262144);  // N*10 ints
  int*   idx2  = (int*)  (ws + 1048576 + 16777216 + 33554432 + 262144 + 2621440);
  float* fmean = (float*)(ws + 1048576 + 16777216 + 33554432 + 262144 + 2621440 + 2621440);

  build_xx<<<256, 256, 0, stream>>>(x, pos, xx);
  knn1_kernel<<<256, 256, 0, stream>>>(xx, idx1);
  edgeconv1_kernel<<<256, 256, 0, stream>>>(xx, idx1, w1a, b1a, w1b, b1b, w1c, b1c, x1, sq2);
  knn2_kernel<<<256, 256, 0, stream>>>(x1, sq2, idx2);
  edgeconv2_kernel<<<512, 256, 0, stream>>>(x1, idx2, w2, b2, x2);
  mean_kernel<<<NB, 192, 0, stream>>>(x1, x2, fmean);
  head_kernel<<<NB, 256, 0, stream>>>(fmean, wl, bl, wm1, bm1, wm2, bm2, wm3, bm3, out);
}